// Round 3
// baseline (474.578 us; speedup 1.0000x reference)
//
#include <hip/hip_runtime.h>
#include <hip/hip_bf16.h>
#include <math.h>

// Problem constants
#define NB 8
#define NS 512
#define NH 768
#define NL 8192

typedef __attribute__((ext_vector_type(8))) __bf16 bf16x8;
typedef __attribute__((ext_vector_type(4))) float f32x4;

static __device__ __forceinline__ f32x4 mfma_bf16(bf16x8 a, bf16x8 b, f32x4 c) {
  return __builtin_amdgcn_mfma_f32_16x16x32_bf16(a, b, c, 0, 0, 0);
}

// async global->LDS, 16B per lane. LDS dest = wave-uniform base + lane*16.
static __device__ __forceinline__ void llds16(const void* g, void* l) {
  __builtin_amdgcn_global_load_lds(
      (const __attribute__((address_space(1))) unsigned int*)g,
      (__attribute__((address_space(3))) unsigned int*)l, 16, 0, 0);
}

// load 8 consecutive fp32 and round-to-nearest to bf16x8
static __device__ __forceinline__ bf16x8 load_cvt8(const float* __restrict__ p) {
  f32x4 u0 = *(const f32x4*)p;
  f32x4 u1 = *(const f32x4*)(p + 4);
  bf16x8 r;
  r[0] = (__bf16)u0[0]; r[1] = (__bf16)u0[1]; r[2] = (__bf16)u0[2]; r[3] = (__bf16)u0[3];
  r[4] = (__bf16)u1[0]; r[5] = (__bf16)u1[1]; r[6] = (__bf16)u1[2]; r[7] = (__bf16)u1[3];
  return r;
}

// ---------------------------------------------------------------------------
// Mask: detect dtype (int8 / int32 / float32) AND expand to 0/-inf bias.
// One block. Probe window = 4096 bytes, in-bounds under every interpretation.
// ---------------------------------------------------------------------------
__global__ void mask_kernel(const unsigned char* __restrict__ m,
                            float* __restrict__ mbias) {
  __shared__ int s_i8, s_f32;
  if (threadIdx.x == 0) { s_i8 = 0; s_f32 = 0; }
  __syncthreads();
  const unsigned int* md = (const unsigned int*)m;
  int li8 = 0, lf = 0;
  for (int i = threadIdx.x; i < 1024; i += blockDim.x) {
    unsigned int d = md[i];
    if (d == 0x3F800000u) lf = 1;
    if (d & 0xFFFFFF00u) li8 = 1;
  }
  if (li8) atomicOr(&s_i8, 1);
  if (lf) atomicOr(&s_f32, 1);
  __syncthreads();
  int f = s_f32 ? 2 : (s_i8 ? 1 : 0);
  for (int i = threadIdx.x; i < NB * NS; i += blockDim.x) {
    int v;
    if (f == 1)      v = (((const unsigned char*)m)[i] != 0);
    else if (f == 2) v = (((const float*)m)[i] != 0.0f);
    else             v = (((const int*)m)[i] != 0);
    mbias[i] = v ? 0.0f : -INFINITY;
  }
}

// ---------------------------------------------------------------------------
// One cast kernel for X|W|E -> contiguous bf16 region at dstbase.
// Region boundaries are multiples of 256 threads -> block-uniform branch.
// ---------------------------------------------------------------------------
#define XT8 393216   // X: 3,145,728 elems / 8
#define WT8 466944   // + W: 589,824 / 8
#define ET8 1253376  // + E: 6,291,456 / 8
__global__ __launch_bounds__(256) void cast_all_kernel(
    const float* __restrict__ X, const float* __restrict__ W,
    const float* __restrict__ E, __bf16* __restrict__ dstbase) {
  size_t t8 = (size_t)blockIdx.x * 256 + threadIdx.x;
  const float* src;
  size_t off;
  if (t8 < XT8)      { src = X; off = t8 * 8; }
  else if (t8 < WT8) { src = W; off = (t8 - XT8) * 8; }
  else               { src = E; off = (t8 - WT8) * 8; }
  bf16x8 v = load_cvt8(src + off);
  *(bf16x8*)(dstbase + t8 * 8) = v;
}

// XT_bf16[b][h][s] = bf16(X[b][s][h]) — padded-LDS tile transpose (verified)
__global__ __launch_bounds__(256) void transpose_kernel(const float* __restrict__ X,
                                                        __bf16* __restrict__ XT) {
  __shared__ float t[64][65];
  const int b = blockIdx.z, s0 = blockIdx.y * 64, h0 = blockIdx.x * 64;
  const int j = threadIdx.x & 63, i0 = threadIdx.x >> 6;
#pragma unroll
  for (int i = i0; i < 64; i += 4) t[i][j] = X[((size_t)b * NS + s0 + i) * NH + h0 + j];
  __syncthreads();
  __bf16* XTb = XT + ((size_t)b * NH + h0) * NS + s0;
  const int si = threadIdx.x & 63, j0 = threadIdx.x >> 6;
#pragma unroll
  for (int jj = j0; jj < 64; jj += 4)
    XTb[(size_t)jj * NS + si] = (__bf16)t[si][jj];
}

// ---------------------------------------------------------------------------
// proj: Kout[m][n] = sum_k Xbf[m][k]*Wbf[n][k]. M=4096,N=768,K=768.
// 64x64 tile, 4 waves (2x2), wave 32x32, BK=32, dbuf 16KB. Grid 768 blocks.
// ---------------------------------------------------------------------------
__global__ __launch_bounds__(256, 4) void proj64_kernel(
    const __bf16* __restrict__ Xbf, const __bf16* __restrict__ Wbf,
    __bf16* __restrict__ Kout) {
  const int tid = threadIdx.x, lane = tid & 63, wid = tid >> 6;
  const int c = lane & 15, g = lane >> 4;
  const int wm = wid >> 1, wn = wid & 1;
  const int m0 = blockIdx.x * 64, n0 = blockIdx.y * 64;
  __shared__ __align__(16) unsigned char Ast[2][4096];
  __shared__ __align__(16) unsigned char Bst[2][4096];

  f32x4 acc[2][2];
#pragma unroll
  for (int i = 0; i < 2; ++i)
#pragma unroll
    for (int j = 0; j < 2; ++j) acc[i][j] = (f32x4){0.f, 0.f, 0.f, 0.f};

  auto stage = [&](int buf, int k0) {
    int idx = wid * 64 + lane;           // chunk = wid
    int row = idx >> 2, slot = idx & 3;
    llds16(Xbf + (size_t)(m0 + row) * NH + k0 + slot * 8, &Ast[buf][wid * 1024]);
    llds16(Wbf + (size_t)(n0 + row) * NH + k0 + slot * 8, &Bst[buf][wid * 1024]);
  };

  stage(0, 0);
  __syncthreads();
  int cur = 0;
  for (int t = 0; t < 24; ++t) {
    if (t < 23) stage(cur ^ 1, (t + 1) * 32);
    bf16x8 af[2], bfr[2];
#pragma unroll
    for (int fm = 0; fm < 2; ++fm)
      af[fm] = *(const bf16x8*)&Ast[cur][(wm * 32 + fm * 16 + c) * 64 + g * 16];
#pragma unroll
    for (int fn = 0; fn < 2; ++fn)
      bfr[fn] = *(const bf16x8*)&Bst[cur][(wn * 32 + fn * 16 + c) * 64 + g * 16];
#pragma unroll
    for (int fm = 0; fm < 2; ++fm)
#pragma unroll
      for (int fn = 0; fn < 2; ++fn)
        acc[fm][fn] = mfma_bf16(af[fm], bfr[fn], acc[fm][fn]);
    __syncthreads();
    cur ^= 1;
  }
#pragma unroll
  for (int fm = 0; fm < 2; ++fm)
#pragma unroll
    for (int r = 0; r < 4; ++r) {
      int row = m0 + wm * 32 + fm * 16 + g * 4 + r;
#pragma unroll
      for (int fn = 0; fn < 2; ++fn)
        Kout[(size_t)row * NH + n0 + wn * 32 + fn * 16 + c] = (__bf16)acc[fm][fn][r];
    }
}

// ---------------------------------------------------------------------------
// Fused: per (b, 64-label tile): staged scores GEMM (K=768) -> in-reg softmax
// -> normalized P (bf16, XOR-swizzled) in LDS -> staged PV (K=512, two 384-col
// halves). 8 waves (512 thr), each wave owns all 64 rows x its column slice.
// LDS: P 64K + stage dbuf 72K + red 2K = 138 KB -> 1 block/CU.
// ---------------------------------------------------------------------------
__global__ __launch_bounds__(512, 1) void fused_attn_kernel(
    const __bf16* __restrict__ Ebf,   // [NL, NH]
    const __bf16* __restrict__ Kbf,   // [NB*NS, NH]
    const __bf16* __restrict__ XTbf,  // [NB, NH, NS]
    const float* __restrict__ mbias,  // [NB*NS] 0 or -inf
    float* __restrict__ Out) {        // [NB*NL, NH]
  const int tid = threadIdx.x, lane = tid & 63, wid = tid >> 6;
  const int c = lane & 15, g = lane >> 4;
  const int b = blockIdx.y;
  const int R0 = blockIdx.x * 64;

  __shared__ __align__(16) __bf16 Plds[64 * 512];        // 65536 B
  __shared__ __align__(16) unsigned char Ast[2][4096];   //  8192 B
  __shared__ __align__(16) unsigned char Bst[2][32768];  // 65536 B
  __shared__ float red[8][64];                           //  2048 B

  const __bf16* Kb0 = Kbf + (size_t)b * NS * NH;

  // ---- Phase 1: scores[64 x 512] = E_tile @ K_b^T, K=768 ----
  f32x4 acc[4][4];
#pragma unroll
  for (int i = 0; i < 4; ++i)
#pragma unroll
    for (int j = 0; j < 4; ++j) acc[i][j] = (f32x4){0.f, 0.f, 0.f, 0.f};

  auto stage1 = [&](int buf, int k0) {
    if (wid < 4) {  // A-tile [64][32]: 4 chunks
      int idx = wid * 64 + lane;
      int row = idx >> 2, slot = idx & 3;
      llds16(Ebf + (size_t)(R0 + row) * NH + k0 + slot * 8, &Ast[buf][wid * 1024]);
    }
#pragma unroll
    for (int it = 0; it < 4; ++it) {  // B-tile [512][32]: 32 chunks
      int ch = it * 8 + wid;
      int idx = ch * 64 + lane;
      int srow = idx >> 2, slot = idx & 3;
      llds16(Kb0 + (size_t)srow * NH + k0 + slot * 8, &Bst[buf][ch * 1024]);
    }
  };

  stage1(0, 0);
  __syncthreads();
  int cur = 0;
  for (int t = 0; t < 24; ++t) {
    if (t < 23) stage1(cur ^ 1, (t + 1) * 32);
    bf16x8 af[4], bfr[4];
#pragma unroll
    for (int fm = 0; fm < 4; ++fm)
      af[fm] = *(const bf16x8*)&Ast[cur][(fm * 16 + c) * 64 + g * 16];
#pragma unroll
    for (int fn = 0; fn < 4; ++fn)
      bfr[fn] = *(const bf16x8*)&Bst[cur][(wid * 64 + fn * 16 + c) * 64 + g * 16];
#pragma unroll
    for (int fm = 0; fm < 4; ++fm)
#pragma unroll
      for (int fn = 0; fn < 4; ++fn)
        acc[fm][fn] = mfma_bf16(af[fm], bfr[fn], acc[fm][fn]);
    __syncthreads();
    cur ^= 1;
  }

  // ---- Phase 2: masked softmax over s (full row = 8 waves x 64 cols) ----
  float bias[4];
#pragma unroll
  for (int fn = 0; fn < 4; ++fn) bias[fn] = mbias[b * NS + wid * 64 + fn * 16 + c];

  // row max
#pragma unroll
  for (int fm = 0; fm < 4; ++fm)
#pragma unroll
    for (int r = 0; r < 4; ++r) {
      float v = -INFINITY;
#pragma unroll
      for (int fn = 0; fn < 4; ++fn) v = fmaxf(v, acc[fm][fn][r] + bias[fn]);
      v = fmaxf(v, __shfl_xor(v, 1));
      v = fmaxf(v, __shfl_xor(v, 2));
      v = fmaxf(v, __shfl_xor(v, 4));
      v = fmaxf(v, __shfl_xor(v, 8));
      if (c == 0) red[wid][fm * 16 + g * 4 + r] = v;
    }
  __syncthreads();
  float rmax[4][4];
#pragma unroll
  for (int fm = 0; fm < 4; ++fm)
#pragma unroll
    for (int r = 0; r < 4; ++r) {
      int l = fm * 16 + g * 4 + r;
      float v = red[0][l];
#pragma unroll
      for (int w = 1; w < 8; ++w) v = fmaxf(v, red[w][l]);
      rmax[fm][r] = v;
    }
  __syncthreads();  // everyone done reading red before reuse

  // exp + row sum (exp stored back into acc)
#pragma unroll
  for (int fm = 0; fm < 4; ++fm)
#pragma unroll
    for (int r = 0; r < 4; ++r) {
      float s = 0.f;
#pragma unroll
      for (int fn = 0; fn < 4; ++fn) {
        float p = __expf(acc[fm][fn][r] + bias[fn] - rmax[fm][r]);
        acc[fm][fn][r] = p;
        s += p;
      }
      s += __shfl_xor(s, 1);
      s += __shfl_xor(s, 2);
      s += __shfl_xor(s, 4);
      s += __shfl_xor(s, 8);
      if (c == 0) red[wid][fm * 16 + g * 4 + r] = s;
    }
  __syncthreads();

  // normalize and write P to LDS (bf16, XOR-swizzled for conflict-free b128 reads)
#pragma unroll
  for (int fm = 0; fm < 4; ++fm)
#pragma unroll
    for (int r = 0; r < 4; ++r) {
      int l = fm * 16 + g * 4 + r;
      float s = red[0][l];
#pragma unroll
      for (int w = 1; w < 8; ++w) s += red[w][l];
      float inv = 1.0f / s;
#pragma unroll
      for (int fn = 0; fn < 4; ++fn) {
        int col = wid * 64 + fn * 16 + c;
        Plds[l * 512 + (col ^ ((l & 7) << 3))] = (__bf16)(acc[fm][fn][r] * inv);
      }
    }
  __syncthreads();  // P complete before PV reads it

  // ---- Phase 3: Out_tile[64 x 768] = P @ X_b^T, K=512, two 384-col halves ----
  const __bf16* XTb0 = XTbf + (size_t)b * NH * NS;
  float* Ob = Out + ((size_t)b * NL + R0) * NH;

  for (int nh = 0; nh < 2; ++nh) {
    const int h0 = nh * 384;
    f32x4 acc2[4][3];
#pragma unroll
    for (int i = 0; i < 4; ++i)
#pragma unroll
      for (int j = 0; j < 3; ++j) acc2[i][j] = (f32x4){0.f, 0.f, 0.f, 0.f};

    auto stage2 = [&](int buf, int ks) {
#pragma unroll
      for (int j = 0; j < 3; ++j) {  // B-tile [384][32]: 24 chunks
        int ch = wid * 3 + j;
        int idx = ch * 64 + lane;
        int hrow = idx >> 2, slot = idx & 3;
        llds16(XTb0 + (size_t)(h0 + hrow) * NS + ks + slot * 8, &Bst[buf][ch * 1024]);
      }
    };

    stage2(0, 0);
    __syncthreads();
    cur = 0;
    for (int t = 0; t < 16; ++t) {
      if (t < 15) stage2(cur ^ 1, (t + 1) * 32);
      int kk = t * 32 + g * 8;
      bf16x8 af[4], bfr[3];
#pragma unroll
      for (int fm = 0; fm < 4; ++fm) {
        int l = fm * 16 + c;
        af[fm] = *(const bf16x8*)&Plds[l * 512 + (kk ^ ((l & 7) << 3))];
      }
#pragma unroll
      for (int fn = 0; fn < 3; ++fn)
        bfr[fn] = *(const bf16x8*)&Bst[cur][(wid * 48 + fn * 16 + c) * 64 + g * 16];
#pragma unroll
      for (int fm = 0; fm < 4; ++fm)
#pragma unroll
        for (int fn = 0; fn < 3; ++fn)
          acc2[fm][fn] = mfma_bf16(af[fm], bfr[fn], acc2[fm][fn]);
      __syncthreads();
      cur ^= 1;
    }
#pragma unroll
    for (int fm = 0; fm < 4; ++fm)
#pragma unroll
      for (int r = 0; r < 4; ++r) {
        int l = fm * 16 + g * 4 + r;
#pragma unroll
        for (int fn = 0; fn < 3; ++fn) {
          int h = h0 + wid * 48 + fn * 16 + c;
          Ob[(size_t)l * NH + h] = acc2[fm][fn][r];
        }
      }
    // next half's stage2(0) is safe: last LDS reads were fenced by loop-final
    // __syncthreads(); epilogue touches only regs + global.
  }
}

// ===========================================================================
// Round-1 fallback path (verified passing) — used only if ws is tiny.
// ===========================================================================
__global__ void detect_mask_kernel(const unsigned char* __restrict__ m,
                                   int* __restrict__ flag) {
  __shared__ int s_i8, s_f32;
  if (threadIdx.x == 0) { s_i8 = 0; s_f32 = 0; }
  __syncthreads();
  const unsigned int* md = (const unsigned int*)m;
  int li8 = 0, lf = 0;
  for (int i = threadIdx.x; i < 1024; i += blockDim.x) {
    unsigned int d = md[i];
    if (d == 0x3F800000u) lf = 1;
    if (d & 0xFFFFFF00u) li8 = 1;
  }
  if (li8) atomicOr(&s_i8, 1);
  if (lf) atomicOr(&s_f32, 1);
  __syncthreads();
  if (threadIdx.x == 0) *flag = s_f32 ? 2 : (s_i8 ? 1 : 0);
}

__global__ void expand_mask_kernel(const void* __restrict__ m,
                                   const int* __restrict__ flag,
                                   float* __restrict__ mbias) {
  int i = blockIdx.x * blockDim.x + threadIdx.x;
  int f = *flag;
  int v;
  if (f == 1)      v = (((const unsigned char*)m)[i] != 0);
  else if (f == 2) v = (((const float*)m)[i] != 0.0f);
  else             v = (((const int*)m)[i] != 0);
  mbias[i] = v ? 0.0f : -INFINITY;
}

__global__ __launch_bounds__(256) void cast_kernel(const float* __restrict__ src,
                                                   __bf16* __restrict__ dst) {
  size_t idx = ((size_t)blockIdx.x * 256 + threadIdx.x) * 8;
  bf16x8 v = load_cvt8(src + idx);
  *(bf16x8*)(dst + idx) = v;
}

__global__ __launch_bounds__(256) void proj_kernel(const float* __restrict__ X,
                                                   const float* __restrict__ W,
                                                   __bf16* __restrict__ Kout) {
  const int tid = threadIdx.x;
  const int lane = tid & 63, wid = tid >> 6;
  const int c = lane & 15, g = lane >> 4;
  const int wm = wid >> 1, wn = wid & 1;
  const int m0 = blockIdx.x * 64 + wm * 32;
  const int n0 = blockIdx.y * 64 + wn * 32;
  f32x4 acc[2][2] = {};
  const float* Xp = X + (size_t)(m0 + c) * NH + g * 8;
  const float* Wp = W + (size_t)(n0 + c) * NH + g * 8;
  for (int k = 0; k < NH; k += 32) {
    bf16x8 a0 = load_cvt8(Xp + k);
    bf16x8 a1 = load_cvt8(Xp + 16 * NH + k);
    bf16x8 b0 = load_cvt8(Wp + k);
    bf16x8 b1 = load_cvt8(Wp + 16 * NH + k);
    acc[0][0] = mfma_bf16(a0, b0, acc[0][0]);
    acc[0][1] = mfma_bf16(a0, b1, acc[0][1]);
    acc[1][0] = mfma_bf16(a1, b0, acc[1][0]);
    acc[1][1] = mfma_bf16(a1, b1, acc[1][1]);
  }
#pragma unroll
  for (int fm = 0; fm < 2; ++fm)
#pragma unroll
    for (int fn = 0; fn < 2; ++fn)
#pragma unroll
      for (int r = 0; r < 4; ++r) {
        int row = m0 + fm * 16 + g * 4 + r;
        int col = n0 + fn * 16 + c;
        Kout[(size_t)row * NH + col] = (__bf16)acc[fm][fn][r];
      }
}

__global__ __launch_bounds__(512) void label_attn_kernel(
    const __bf16* __restrict__ Ebf, const __bf16* __restrict__ Kbf,
    const __bf16* __restrict__ XTbf, const float* __restrict__ mbias,
    float* __restrict__ Out) {
  const int tid = threadIdx.x;
  const int lane = tid & 63, wid = tid >> 6;
  const int c = lane & 15, g = lane >> 4;
  const int wm = wid >> 2, wn = wid & 3;
  const int b = blockIdx.y;
  const int R0 = blockIdx.x * 64;
  __shared__ alignas(16) __bf16 Plds[64 * 512];
  __shared__ float redM[4][64];
  __shared__ float redS[4][64];
  f32x4 acc[2][8];
#pragma unroll
  for (int i = 0; i < 2; ++i)
#pragma unroll
    for (int j = 0; j < 8; ++j) acc[i][j] = (f32x4){0.f, 0.f, 0.f, 0.f};
  const __bf16* Ea = Ebf + (size_t)(R0 + wm * 32 + c) * NH + g * 8;
  const __bf16* Kb = Kbf + ((size_t)b * NS + wn * 128 + c) * NH + g * 8;
  float bias[8];
#pragma unroll
  for (int fn = 0; fn < 8; ++fn) bias[fn] = mbias[b * NS + wn * 128 + fn * 16 + c];
  for (int k = 0; k < NH; k += 32) {
    bf16x8 a0 = *(const bf16x8*)(Ea + k);
    bf16x8 a1 = *(const bf16x8*)(Ea + 16 * NH + k);
#pragma unroll
    for (int fn = 0; fn < 8; ++fn) {
      bf16x8 bb = *(const bf16x8*)(Kb + (size_t)fn * 16 * NH + k);
      acc[0][fn] = mfma_bf16(a0, bb, acc[0][fn]);
      acc[1][fn] = mfma_bf16(a1, bb, acc[1][fn]);
    }
  }
  float pmax[2][4];
#pragma unroll
  for (int fm = 0; fm < 2; ++fm)
#pragma unroll
    for (int r = 0; r < 4; ++r) {
      float v = -INFINITY;
#pragma unroll
      for (int fn = 0; fn < 8; ++fn) v = fmaxf(v, acc[fm][fn][r] + bias[fn]);
#pragma unroll
      for (int off = 1; off < 16; off <<= 1) v = fmaxf(v, __shfl_xor(v, off));
      pmax[fm][r] = v;
    }
  if (c == 0) {
#pragma unroll
    for (int fm = 0; fm < 2; ++fm)
#pragma unroll
      for (int r = 0; r < 4; ++r)
        redM[wn][wm * 32 + fm * 16 + g * 4 + r] = pmax[fm][r];
  }
  __syncthreads();
  float rmax[2][4];
#pragma unroll
  for (int fm = 0; fm < 2; ++fm)
#pragma unroll
    for (int r = 0; r < 4; ++r) {
      int row = wm * 32 + fm * 16 + g * 4 + r;
      rmax[fm][r] = fmaxf(fmaxf(redM[0][row], redM[1][row]),
                          fmaxf(redM[2][row], redM[3][row]));
    }
  float psum[2][4] = {{0.f, 0.f, 0.f, 0.f}, {0.f, 0.f, 0.f, 0.f}};
#pragma unroll
  for (int fm = 0; fm < 2; ++fm)
#pragma unroll
    for (int fn = 0; fn < 8; ++fn) {
      int col = wn * 128 + fn * 16 + c;
#pragma unroll
      for (int r = 0; r < 4; ++r) {
        int row = wm * 32 + fm * 16 + g * 4 + r;
        float p = __expf(acc[fm][fn][r] + bias[fn] - rmax[fm][r]);
        psum[fm][r] += p;
        Plds[row * 512 + (col ^ ((row & 7) << 3))] = (__bf16)p;
      }
    }
#pragma unroll
  for (int fm = 0; fm < 2; ++fm)
#pragma unroll
    for (int r = 0; r < 4; ++r) {
      float v = psum[fm][r];
#pragma unroll
      for (int off = 1; off < 16; off <<= 1) v += __shfl_xor(v, off);
      psum[fm][r] = v;
    }
  if (c == 0) {
#pragma unroll
    for (int fm = 0; fm < 2; ++fm)
#pragma unroll
      for (int r = 0; r < 4; ++r)
        redS[wn][wm * 32 + fm * 16 + g * 4 + r] = psum[fm][r];
  }
  __syncthreads();
  float inv[2][4];
#pragma unroll
  for (int fm = 0; fm < 2; ++fm)
#pragma unroll
    for (int r = 0; r < 4; ++r) {
      int row = wm * 32 + fm * 16 + g * 4 + r;
      float s = redS[0][row] + redS[1][row] + redS[2][row] + redS[3][row];
      inv[fm][r] = 1.0f / s;
    }
  f32x4 acc2[2][12];
#pragma unroll
  for (int i = 0; i < 2; ++i)
#pragma unroll
    for (int j = 0; j < 12; ++j) acc2[i][j] = (f32x4){0.f, 0.f, 0.f, 0.f};
  const __bf16* XTb = XTbf + ((size_t)b * NH + wn * 192 + c) * NS + g * 8;
  const int r0 = wm * 32 + c;
  const int r1 = r0 + 16;
  for (int ks = 0; ks < NS; ks += 32) {
    int kk = ks + g * 8;
    bf16x8 a0 = *(const bf16x8*)&Plds[r0 * 512 + (kk ^ ((r0 & 7) << 3))];
    bf16x8 a1 = *(const bf16x8*)&Plds[r1 * 512 + (kk ^ ((r1 & 7) << 3))];
#pragma unroll
    for (int fn = 0; fn < 12; ++fn) {
      bf16x8 bb = *(const bf16x8*)(XTb + (size_t)fn * 16 * NS + ks);
      acc2[0][fn] = mfma_bf16(a0, bb, acc2[0][fn]);
      acc2[1][fn] = mfma_bf16(a1, bb, acc2[1][fn]);
    }
  }
  float* Ob = Out + ((size_t)b * NL + R0) * NH;
#pragma unroll
  for (int fm = 0; fm < 2; ++fm)
#pragma unroll
    for (int r = 0; r < 4; ++r) {
      int row = wm * 32 + fm * 16 + g * 4 + r;
      float sc = inv[fm][r];
#pragma unroll
      for (int fn = 0; fn < 12; ++fn) {
        int h = wn * 192 + fn * 16 + c;
        Ob[(size_t)row * NH + h] = acc2[fm][fn][r] * sc;
      }
    }
}

// ---------------------------------------------------------------------------
extern "C" void kernel_launch(void* const* d_in, const int* in_sizes, int n_in,
                              void* d_out, int out_size, void* d_ws, size_t ws_size,
                              hipStream_t stream) {
  const float* X = (const float*)d_in[0];   // [8,512,768] f32
  const void* masks = d_in[1];              // [8,1,512] bool (dtype probed)
  const float* E = (const float*)d_in[2];   // [8192,768] f32
  const float* W = (const float*)d_in[3];   // [768,768] f32
  float* Out = (float*)d_out;               // [8,8192,768] f32

  char* ws = (char*)d_ws;
  const size_t NEED = 32653312;

  if (ws_size >= NEED) {
    // ---- fused path: 5 launches ----
    __bf16* Xbf  = (__bf16*)ws;                    //  6,291,456 B
    __bf16* Wbf  = (__bf16*)(ws + 6291456);        //  1,179,648 B
    __bf16* Ebf  = (__bf16*)(ws + 7471104);        // 12,582,912 B
    __bf16* Kbf  = (__bf16*)(ws + 20054016);       //  6,291,456 B
    __bf16* XTbf = (__bf16*)(ws + 26345472);       //  6,291,456 B
    float* mbias = (float*)(ws + 32636928);        //     16,384 B

    mask_kernel<<<1, 256, 0, stream>>>((const unsigned char*)masks, mbias);
    cast_all_kernel<<<4896, 256, 0, stream>>>(X, W, E, Xbf);
    transpose_kernel<<<dim3(12, 8, 8), 256, 0, stream>>>(X, XTbf);
    proj64_kernel<<<dim3(64, 12), 256, 0, stream>>>(Xbf, Wbf, Kbf);
    fused_attn_kernel<<<dim3(128, 8), 512, 0, stream>>>(Ebf, Kbf, XTbf, mbias, Out);
  } else {
    // ---- round-1 fallback (25.2 MB ws) ----
    __bf16* Kbf  = (__bf16*)ws;
    __bf16* XTbf = (__bf16*)(ws + 6291456);
    __bf16* Ebf  = (__bf16*)(ws + 12582912);
    float* mbias = (float*)(ws + 25165824);
    int* flag    = (int*)(ws + 25182208);

    detect_mask_kernel<<<1, 256, 0, stream>>>((const unsigned char*)masks, flag);
    expand_mask_kernel<<<16, 256, 0, stream>>>(masks, flag, mbias);
    proj_kernel<<<dim3(64, 12), 256, 0, stream>>>(X, W, Kbf);
    transpose_kernel<<<dim3(12, 8, 8), 256, 0, stream>>>(X, XTbf);
    cast_kernel<<<3072, 256, 0, stream>>>(E, Ebf);
    label_attn_kernel<<<dim3(128, 8), 512, 0, stream>>>(Ebf, Kbf, XTbf, mbias, Out);
  }
}

// Round 4
// 457.404 us; speedup vs baseline: 1.0375x; 1.0375x over previous
//
#include <hip/hip_runtime.h>
#include <hip/hip_bf16.h>
#include <math.h>

// Problem constants
#define NB 8
#define NS 512
#define NH 768
#define NL 8192

typedef __attribute__((ext_vector_type(8))) __bf16 bf16x8;
typedef __attribute__((ext_vector_type(4))) float f32x4;

static __device__ __forceinline__ f32x4 mfma_bf16(bf16x8 a, bf16x8 b, f32x4 c) {
  return __builtin_amdgcn_mfma_f32_16x16x32_bf16(a, b, c, 0, 0, 0);
}

// async global->LDS, 16B per lane. LDS dest = wave-uniform base + lane*16.
static __device__ __forceinline__ void llds16(const void* g, void* l) {
  __builtin_amdgcn_global_load_lds(
      (const __attribute__((address_space(1))) unsigned int*)g,
      (__attribute__((address_space(3))) unsigned int*)l, 16, 0, 0);
}

// load 8 consecutive fp32 and round-to-nearest to bf16x8
static __device__ __forceinline__ bf16x8 load_cvt8(const float* __restrict__ p) {
  f32x4 u0 = *(const f32x4*)p;
  f32x4 u1 = *(const f32x4*)(p + 4);
  bf16x8 r;
  r[0] = (__bf16)u0[0]; r[1] = (__bf16)u0[1]; r[2] = (__bf16)u0[2]; r[3] = (__bf16)u0[3];
  r[4] = (__bf16)u1[0]; r[5] = (__bf16)u1[1]; r[6] = (__bf16)u1[2]; r[7] = (__bf16)u1[3];
  return r;
}

// ---------------------------------------------------------------------------
// Mask: detect dtype (int8 / int32 / float32) AND expand to 0/-inf bias.
// One block. Probe window = 4096 bytes, in-bounds under every interpretation.
// ---------------------------------------------------------------------------
__global__ void mask_kernel(const unsigned char* __restrict__ m,
                            float* __restrict__ mbias) {
  __shared__ int s_i8, s_f32;
  if (threadIdx.x == 0) { s_i8 = 0; s_f32 = 0; }
  __syncthreads();
  const unsigned int* md = (const unsigned int*)m;
  int li8 = 0, lf = 0;
  for (int i = threadIdx.x; i < 1024; i += blockDim.x) {
    unsigned int d = md[i];
    if (d == 0x3F800000u) lf = 1;
    if (d & 0xFFFFFF00u) li8 = 1;
  }
  if (li8) atomicOr(&s_i8, 1);
  if (lf) atomicOr(&s_f32, 1);
  __syncthreads();
  int f = s_f32 ? 2 : (s_i8 ? 1 : 0);
  for (int i = threadIdx.x; i < NB * NS; i += blockDim.x) {
    int v;
    if (f == 1)      v = (((const unsigned char*)m)[i] != 0);
    else if (f == 2) v = (((const float*)m)[i] != 0.0f);
    else             v = (((const int*)m)[i] != 0);
    mbias[i] = v ? 0.0f : -INFINITY;
  }
}

// ---------------------------------------------------------------------------
// prep: casts (X|W|E -> contiguous bf16 at dstbase) + X transpose, one kernel.
// Region boundaries are multiples of 256 threads -> block-uniform branch.
// ---------------------------------------------------------------------------
#define XT8 393216   // X: 3,145,728 elems / 8
#define WT8 466944   // + W: 589,824 / 8
#define ET8 1253376  // + E: 6,291,456 / 8
#define CAST_BLOCKS 4896
__global__ __launch_bounds__(256) void prep_kernel(
    const float* __restrict__ X, const float* __restrict__ W,
    const float* __restrict__ E, __bf16* __restrict__ dstbase,
    __bf16* __restrict__ XT) {
  __shared__ float t[64][65];
  const int bx = blockIdx.x;
  if (bx < CAST_BLOCKS) {
    size_t t8 = (size_t)bx * 256 + threadIdx.x;
    const float* src;
    size_t off;
    if (t8 < XT8)      { src = X; off = t8 * 8; }
    else if (t8 < WT8) { src = W; off = (t8 - XT8) * 8; }
    else               { src = E; off = (t8 - WT8) * 8; }
    bf16x8 v = load_cvt8(src + off);
    *(bf16x8*)(dstbase + t8 * 8) = v;
  } else {
    // transpose region: 768 blocks -> XT[b][h][s] = bf16(X[b][s][h])
    const int tb = bx - CAST_BLOCKS;        // 0..767
    const int hb = tb % 12, sb = (tb / 12) % 8, b = tb / 96;
    const int s0 = sb * 64, h0 = hb * 64;
    const int j = threadIdx.x & 63, i0 = threadIdx.x >> 6;
#pragma unroll
    for (int i = i0; i < 64; i += 4)
      t[i][j] = X[((size_t)b * NS + s0 + i) * NH + h0 + j];
    __syncthreads();
    __bf16* XTb = XT + ((size_t)b * NH + h0) * NS + s0;
    const int si = threadIdx.x & 63, j0 = threadIdx.x >> 6;
#pragma unroll
    for (int jj = j0; jj < 64; jj += 4)
      XTb[(size_t)jj * NS + si] = (__bf16)t[si][jj];
  }
}

// ---------------------------------------------------------------------------
// proj: Kout[m][n] = sum_k Xbf[m][k]*Wbf[n][k]. M=4096,N=768,K=768.
// 64x64 tile, 4 waves (2x2), wave 32x32, BK=32, dbuf 16KB. Grid 768 blocks.
// (R3-verified.)
// ---------------------------------------------------------------------------
__global__ __launch_bounds__(256, 4) void proj64_kernel(
    const __bf16* __restrict__ Xbf, const __bf16* __restrict__ Wbf,
    __bf16* __restrict__ Kout) {
  const int tid = threadIdx.x, lane = tid & 63, wid = tid >> 6;
  const int c = lane & 15, g = lane >> 4;
  const int wm = wid >> 1, wn = wid & 1;
  const int m0 = blockIdx.x * 64, n0 = blockIdx.y * 64;
  __shared__ __align__(16) unsigned char Ast[2][4096];
  __shared__ __align__(16) unsigned char Bst[2][4096];

  f32x4 acc[2][2];
#pragma unroll
  for (int i = 0; i < 2; ++i)
#pragma unroll
    for (int j = 0; j < 2; ++j) acc[i][j] = (f32x4){0.f, 0.f, 0.f, 0.f};

  auto stage = [&](int buf, int k0) {
    int idx = wid * 64 + lane;
    int row = idx >> 2, slot = idx & 3;
    llds16(Xbf + (size_t)(m0 + row) * NH + k0 + slot * 8, &Ast[buf][wid * 1024]);
    llds16(Wbf + (size_t)(n0 + row) * NH + k0 + slot * 8, &Bst[buf][wid * 1024]);
  };

  stage(0, 0);
  __syncthreads();
  int cur = 0;
  for (int t = 0; t < 24; ++t) {
    if (t < 23) stage(cur ^ 1, (t + 1) * 32);
    bf16x8 af[2], bfr[2];
#pragma unroll
    for (int fm = 0; fm < 2; ++fm)
      af[fm] = *(const bf16x8*)&Ast[cur][(wm * 32 + fm * 16 + c) * 64 + g * 16];
#pragma unroll
    for (int fn = 0; fn < 2; ++fn)
      bfr[fn] = *(const bf16x8*)&Bst[cur][(wn * 32 + fn * 16 + c) * 64 + g * 16];
#pragma unroll
    for (int fm = 0; fm < 2; ++fm)
#pragma unroll
      for (int fn = 0; fn < 2; ++fn)
        acc[fm][fn] = mfma_bf16(af[fm], bfr[fn], acc[fm][fn]);
    __syncthreads();
    cur ^= 1;
  }
#pragma unroll
  for (int fm = 0; fm < 2; ++fm)
#pragma unroll
    for (int r = 0; r < 4; ++r) {
      int row = m0 + wm * 32 + fm * 16 + g * 4 + r;
#pragma unroll
      for (int fn = 0; fn < 2; ++fn)
        Kout[(size_t)row * NH + n0 + wn * 32 + fn * 16 + c] = (__bf16)acc[fm][fn][r];
    }
}

// ---------------------------------------------------------------------------
// scores64: per (b, 64-label tile): staged scores GEMM (K=768) -> in-reg
// softmax -> normalized P repacked via LDS -> coalesced bf16 store to Pws.
// R3-verified phase1+2; phase-3 replaced by coalesced flush.
// LDS: Ast 8K + Bst 64K + red 2K = 74 KB; VGPR ~96 -> 2 blocks/CU.
// ---------------------------------------------------------------------------
__global__ __launch_bounds__(512, 4) void scores64_kernel(
    const __bf16* __restrict__ Ebf,   // [NL, NH]
    const __bf16* __restrict__ Kbf,   // [NB*NS, NH]
    const float* __restrict__ mbias,  // [NB*NS] 0 or -inf
    __bf16* __restrict__ Pws) {       // [NB*NL, NS] normalized P
  const int tid = threadIdx.x, lane = tid & 63, wid = tid >> 6;
  const int c = lane & 15, g = lane >> 4;
  const int b = blockIdx.y;
  const int R0 = blockIdx.x * 64;

  __shared__ __align__(16) unsigned char Ast[2][4096];   //  8192 B
  __shared__ __align__(16) unsigned char Bst[2][32768];  // 65536 B
  __shared__ float red[8][64];                           //  2048 B

  const __bf16* Kb0 = Kbf + (size_t)b * NS * NH;

  // ---- Phase 1: scores[64 x 512] = E_tile @ K_b^T, K=768 ----
  f32x4 acc[4][4];
#pragma unroll
  for (int i = 0; i < 4; ++i)
#pragma unroll
    for (int j = 0; j < 4; ++j) acc[i][j] = (f32x4){0.f, 0.f, 0.f, 0.f};

  auto stage1 = [&](int buf, int k0) {
    if (wid < 4) {  // A-tile [64][32]: 4 chunks
      int idx = wid * 64 + lane;
      int row = idx >> 2, slot = idx & 3;
      llds16(Ebf + (size_t)(R0 + row) * NH + k0 + slot * 8, &Ast[buf][wid * 1024]);
    }
#pragma unroll
    for (int it = 0; it < 4; ++it) {  // B-tile [512][32]: 32 chunks
      int ch = it * 8 + wid;
      int idx = ch * 64 + lane;
      int srow = idx >> 2, slot = idx & 3;
      llds16(Kb0 + (size_t)srow * NH + k0 + slot * 8, &Bst[buf][ch * 1024]);
    }
  };

  stage1(0, 0);
  __syncthreads();
  int cur = 0;
  for (int t = 0; t < 24; ++t) {
    if (t < 23) stage1(cur ^ 1, (t + 1) * 32);
    bf16x8 af[4], bfr[4];
#pragma unroll
    for (int fm = 0; fm < 4; ++fm)
      af[fm] = *(const bf16x8*)&Ast[cur][(fm * 16 + c) * 64 + g * 16];
#pragma unroll
    for (int fn = 0; fn < 4; ++fn)
      bfr[fn] = *(const bf16x8*)&Bst[cur][(wid * 64 + fn * 16 + c) * 64 + g * 16];
#pragma unroll
    for (int fm = 0; fm < 4; ++fm)
#pragma unroll
      for (int fn = 0; fn < 4; ++fn)
        acc[fm][fn] = mfma_bf16(af[fm], bfr[fn], acc[fm][fn]);
    __syncthreads();
    cur ^= 1;
  }

  // ---- Phase 2: masked softmax over s (full row = 8 waves x 64 cols) ----
  float bias[4];
#pragma unroll
  for (int fn = 0; fn < 4; ++fn) bias[fn] = mbias[b * NS + wid * 64 + fn * 16 + c];

  // row max
#pragma unroll
  for (int fm = 0; fm < 4; ++fm)
#pragma unroll
    for (int r = 0; r < 4; ++r) {
      float v = -INFINITY;
#pragma unroll
      for (int fn = 0; fn < 4; ++fn) v = fmaxf(v, acc[fm][fn][r] + bias[fn]);
      v = fmaxf(v, __shfl_xor(v, 1));
      v = fmaxf(v, __shfl_xor(v, 2));
      v = fmaxf(v, __shfl_xor(v, 4));
      v = fmaxf(v, __shfl_xor(v, 8));
      if (c == 0) red[wid][fm * 16 + g * 4 + r] = v;
    }
  __syncthreads();
  float rmax[4][4];
#pragma unroll
  for (int fm = 0; fm < 4; ++fm)
#pragma unroll
    for (int r = 0; r < 4; ++r) {
      int l = fm * 16 + g * 4 + r;
      float v = red[0][l];
#pragma unroll
      for (int w = 1; w < 8; ++w) v = fmaxf(v, red[w][l]);
      rmax[fm][r] = v;
    }
  __syncthreads();  // all reads of red done before reuse

  // exp + row sum (exp stored back into acc)
#pragma unroll
  for (int fm = 0; fm < 4; ++fm)
#pragma unroll
    for (int r = 0; r < 4; ++r) {
      float s = 0.f;
#pragma unroll
      for (int fn = 0; fn < 4; ++fn) {
        float p = __expf(acc[fm][fn][r] + bias[fn] - rmax[fm][r]);
        acc[fm][fn][r] = p;
        s += p;
      }
      s += __shfl_xor(s, 1);
      s += __shfl_xor(s, 2);
      s += __shfl_xor(s, 4);
      s += __shfl_xor(s, 8);
      if (c == 0) red[wid][fm * 16 + g * 4 + r] = s;
    }
  __syncthreads();

  // normalize; repack normalized bf16 P into LDS (reuse Bst: 64x512 = 64 KB)
  __bf16* Plin = (__bf16*)Bst;
#pragma unroll
  for (int fm = 0; fm < 4; ++fm)
#pragma unroll
    for (int r = 0; r < 4; ++r) {
      int l = fm * 16 + g * 4 + r;
      float s = red[0][l];
#pragma unroll
      for (int w = 1; w < 8; ++w) s += red[w][l];
      float inv = 1.0f / s;
#pragma unroll
      for (int fn = 0; fn < 4; ++fn) {
        int col = wid * 64 + fn * 16 + c;
        Plin[l * 512 + col] = (__bf16)(acc[fm][fn][r] * inv);
      }
    }
  __syncthreads();  // P complete in LDS

  // coalesced flush: wave w -> rows w*8..w*8+7, 16 B per lane
  __bf16* Pb = Pws + ((size_t)b * NL + R0) * NS;
#pragma unroll
  for (int i = 0; i < 8; ++i) {
    int row = wid * 8 + i;
    bf16x8 v = *(const bf16x8*)&Plin[row * 512 + lane * 8];
    *(bf16x8*)(Pb + (size_t)row * NS + lane * 8) = v;
  }
}

// ---------------------------------------------------------------------------
// pv: Out = P @ X (per b). m97-clone: M=NL, N=768, K=512, 128x128 tile,
// 4 waves (2x2), wave 64x64, BK=32, LDS dbuf 32KB. (R2-verified.)
// ---------------------------------------------------------------------------
__global__ __launch_bounds__(256, 3) void pv_kernel(
    const __bf16* __restrict__ Pws,   // [NB*NL, NS]
    const __bf16* __restrict__ XTbf,  // [NB, NH, NS]
    float* __restrict__ Out) {        // [NB*NL, NH]
  const int tid = threadIdx.x, lane = tid & 63, wid = tid >> 6;
  const int c = lane & 15, g = lane >> 4;
  const int wm = wid >> 1, wn = wid & 1;
  const int b = blockIdx.z;
  const size_t rowbase = (size_t)b * NL + (size_t)blockIdx.x * 128;
  const int h0 = blockIdx.y * 128;
  __shared__ __align__(16) unsigned char smem[2][16384];
  const __bf16* Xb0 = XTbf + (size_t)b * NH * NS;

  f32x4 acc[4][4];
#pragma unroll
  for (int i = 0; i < 4; ++i)
#pragma unroll
    for (int j = 0; j < 4; ++j) acc[i][j] = (f32x4){0.f, 0.f, 0.f, 0.f};

  auto stage = [&](int buf, int k0) {
#pragma unroll
    for (int it = 0; it < 2; ++it) {
      int ch = it * 4 + wid;
      int idx = ch * 64 + lane;
      int row = idx >> 2, slot = idx & 3;
      llds16(Pws + (rowbase + row) * NS + k0 + slot * 8, &smem[buf][ch * 1024]);
      llds16(Xb0 + (size_t)(h0 + row) * NS + k0 + slot * 8, &smem[buf][8192 + ch * 1024]);
    }
  };

  stage(0, 0);
  __syncthreads();
  int cur = 0;
  for (int t = 0; t < 16; ++t) {
    if (t < 15) stage(cur ^ 1, (t + 1) * 32);
    const unsigned char* A = smem[cur];
    const unsigned char* B = smem[cur] + 8192;
    bf16x8 af[4], bfr[4];
#pragma unroll
    for (int fm = 0; fm < 4; ++fm)
      af[fm] = *(const bf16x8*)(A + (wm * 64 + fm * 16 + c) * 64 + g * 16);
#pragma unroll
    for (int fn = 0; fn < 4; ++fn)
      bfr[fn] = *(const bf16x8*)(B + (wn * 64 + fn * 16 + c) * 64 + g * 16);
#pragma unroll
    for (int fm = 0; fm < 4; ++fm)
#pragma unroll
      for (int fn = 0; fn < 4; ++fn)
        acc[fm][fn] = mfma_bf16(af[fm], bfr[fn], acc[fm][fn]);
    __syncthreads();
    cur ^= 1;
  }
  float* Ob = Out + rowbase * NH;
#pragma unroll
  for (int fm = 0; fm < 4; ++fm)
#pragma unroll
    for (int r = 0; r < 4; ++r) {
      int row = wm * 64 + fm * 16 + g * 4 + r;
#pragma unroll
      for (int fn = 0; fn < 4; ++fn)
        Ob[(size_t)row * NH + h0 + wn * 64 + fn * 16 + c] = acc[fm][fn][r];
    }
}

// ===========================================================================
// Round-1 fallback path (verified passing) — used only if ws is tiny.
// ===========================================================================
__global__ void detect_mask_kernel(const unsigned char* __restrict__ m,
                                   int* __restrict__ flag) {
  __shared__ int s_i8, s_f32;
  if (threadIdx.x == 0) { s_i8 = 0; s_f32 = 0; }
  __syncthreads();
  const unsigned int* md = (const unsigned int*)m;
  int li8 = 0, lf = 0;
  for (int i = threadIdx.x; i < 1024; i += blockDim.x) {
    unsigned int d = md[i];
    if (d == 0x3F800000u) lf = 1;
    if (d & 0xFFFFFF00u) li8 = 1;
  }
  if (li8) atomicOr(&s_i8, 1);
  if (lf) atomicOr(&s_f32, 1);
  __syncthreads();
  if (threadIdx.x == 0) *flag = s_f32 ? 2 : (s_i8 ? 1 : 0);
}

__global__ void expand_mask_kernel(const void* __restrict__ m,
                                   const int* __restrict__ flag,
                                   float* __restrict__ mbias) {
  int i = blockIdx.x * blockDim.x + threadIdx.x;
  int f = *flag;
  int v;
  if (f == 1)      v = (((const unsigned char*)m)[i] != 0);
  else if (f == 2) v = (((const float*)m)[i] != 0.0f);
  else             v = (((const int*)m)[i] != 0);
  mbias[i] = v ? 0.0f : -INFINITY;
}

__global__ __launch_bounds__(256) void cast_kernel(const float* __restrict__ src,
                                                   __bf16* __restrict__ dst) {
  size_t idx = ((size_t)blockIdx.x * 256 + threadIdx.x) * 8;
  bf16x8 v = load_cvt8(src + idx);
  *(bf16x8*)(dst + idx) = v;
}

__global__ __launch_bounds__(256) void transpose_kernel(const float* __restrict__ X,
                                                        __bf16* __restrict__ XT) {
  __shared__ float t[64][65];
  const int b = blockIdx.z, s0 = blockIdx.y * 64, h0 = blockIdx.x * 64;
  const int j = threadIdx.x & 63, i0 = threadIdx.x >> 6;
#pragma unroll
  for (int i = i0; i < 64; i += 4) t[i][j] = X[((size_t)b * NS + s0 + i) * NH + h0 + j];
  __syncthreads();
  __bf16* XTb = XT + ((size_t)b * NH + h0) * NS + s0;
  const int si = threadIdx.x & 63, j0 = threadIdx.x >> 6;
#pragma unroll
  for (int jj = j0; jj < 64; jj += 4)
    XTb[(size_t)jj * NS + si] = (__bf16)t[si][jj];
}

__global__ __launch_bounds__(256) void proj_kernel(const float* __restrict__ X,
                                                   const float* __restrict__ W,
                                                   __bf16* __restrict__ Kout) {
  const int tid = threadIdx.x;
  const int lane = tid & 63, wid = tid >> 6;
  const int c = lane & 15, g = lane >> 4;
  const int wm = wid >> 1, wn = wid & 1;
  const int m0 = blockIdx.x * 64 + wm * 32;
  const int n0 = blockIdx.y * 64 + wn * 32;
  f32x4 acc[2][2] = {};
  const float* Xp = X + (size_t)(m0 + c) * NH + g * 8;
  const float* Wp = W + (size_t)(n0 + c) * NH + g * 8;
  for (int k = 0; k < NH; k += 32) {
    bf16x8 a0 = load_cvt8(Xp + k);
    bf16x8 a1 = load_cvt8(Xp + 16 * NH + k);
    bf16x8 b0 = load_cvt8(Wp + k);
    bf16x8 b1 = load_cvt8(Wp + 16 * NH + k);
    acc[0][0] = mfma_bf16(a0, b0, acc[0][0]);
    acc[0][1] = mfma_bf16(a0, b1, acc[0][1]);
    acc[1][0] = mfma_bf16(a1, b0, acc[1][0]);
    acc[1][1] = mfma_bf16(a1, b1, acc[1][1]);
  }
#pragma unroll
  for (int fm = 0; fm < 2; ++fm)
#pragma unroll
    for (int fn = 0; fn < 2; ++fn)
#pragma unroll
      for (int r = 0; r < 4; ++r) {
        int row = m0 + fm * 16 + g * 4 + r;
        int col = n0 + fn * 16 + c;
        Kout[(size_t)row * NH + col] = (__bf16)acc[fm][fn][r];
      }
}

__global__ __launch_bounds__(512) void label_attn_kernel(
    const __bf16* __restrict__ Ebf, const __bf16* __restrict__ Kbf,
    const __bf16* __restrict__ XTbf, const float* __restrict__ mbias,
    float* __restrict__ Out) {
  const int tid = threadIdx.x;
  const int lane = tid & 63, wid = tid >> 6;
  const int c = lane & 15, g = lane >> 4;
  const int wm = wid >> 2, wn = wid & 3;
  const int b = blockIdx.y;
  const int R0 = blockIdx.x * 64;
  __shared__ alignas(16) __bf16 Plds[64 * 512];
  __shared__ float redM[4][64];
  __shared__ float redS[4][64];
  f32x4 acc[2][8];
#pragma unroll
  for (int i = 0; i < 2; ++i)
#pragma unroll
    for (int j = 0; j < 8; ++j) acc[i][j] = (f32x4){0.f, 0.f, 0.f, 0.f};
  const __bf16* Ea = Ebf + (size_t)(R0 + wm * 32 + c) * NH + g * 8;
  const __bf16* Kb = Kbf + ((size_t)b * NS + wn * 128 + c) * NH + g * 8;
  float bias[8];
#pragma unroll
  for (int fn = 0; fn < 8; ++fn) bias[fn] = mbias[b * NS + wn * 128 + fn * 16 + c];
  for (int k = 0; k < NH; k += 32) {
    bf16x8 a0 = *(const bf16x8*)(Ea + k);
    bf16x8 a1 = *(const bf16x8*)(Ea + 16 * NH + k);
#pragma unroll
    for (int fn = 0; fn < 8; ++fn) {
      bf16x8 bb = *(const bf16x8*)(Kb + (size_t)fn * 16 * NH + k);
      acc[0][fn] = mfma_bf16(a0, bb, acc[0][fn]);
      acc[1][fn] = mfma_bf16(a1, bb, acc[1][fn]);
    }
  }
  float pmax[2][4];
#pragma unroll
  for (int fm = 0; fm < 2; ++fm)
#pragma unroll
    for (int r = 0; r < 4; ++r) {
      float v = -INFINITY;
#pragma unroll
      for (int fn = 0; fn < 8; ++fn) v = fmaxf(v, acc[fm][fn][r] + bias[fn]);
#pragma unroll
      for (int off = 1; off < 16; off <<= 1) v = fmaxf(v, __shfl_xor(v, off));
      pmax[fm][r] = v;
    }
  if (c == 0) {
#pragma unroll
    for (int fm = 0; fm < 2; ++fm)
#pragma unroll
      for (int r = 0; r < 4; ++r)
        redM[wn][wm * 32 + fm * 16 + g * 4 + r] = pmax[fm][r];
  }
  __syncthreads();
  float rmax[2][4];
#pragma unroll
  for (int fm = 0; fm < 2; ++fm)
#pragma unroll
    for (int r = 0; r < 4; ++r) {
      int row = wm * 32 + fm * 16 + g * 4 + r;
      rmax[fm][r] = fmaxf(fmaxf(redM[0][row], redM[1][row]),
                          fmaxf(redM[2][row], redM[3][row]));
    }
  float psum[2][4] = {{0.f, 0.f, 0.f, 0.f}, {0.f, 0.f, 0.f, 0.f}};
#pragma unroll
  for (int fm = 0; fm < 2; ++fm)
#pragma unroll
    for (int fn = 0; fn < 8; ++fn) {
      int col = wn * 128 + fn * 16 + c;
#pragma unroll
      for (int r = 0; r < 4; ++r) {
        int row = wm * 32 + fm * 16 + g * 4 + r;
        float p = __expf(acc[fm][fn][r] + bias[fn] - rmax[fm][r]);
        psum[fm][r] += p;
        Plds[row * 512 + (col ^ ((row & 7) << 3))] = (__bf16)p;
      }
    }
#pragma unroll
  for (int fm = 0; fm < 2; ++fm)
#pragma unroll
    for (int r = 0; r < 4; ++r) {
      float v = psum[fm][r];
#pragma unroll
      for (int off = 1; off < 16; off <<= 1) v += __shfl_xor(v, off);
      psum[fm][r] = v;
    }
  if (c == 0) {
#pragma unroll
    for (int fm = 0; fm < 2; ++fm)
#pragma unroll
      for (int r = 0; r < 4; ++r)
        redS[wn][wm * 32 + fm * 16 + g * 4 + r] = psum[fm][r];
  }
  __syncthreads();
  float inv[2][4];
#pragma unroll
  for (int fm = 0; fm < 2; ++fm)
#pragma unroll
    for (int r = 0; r < 4; ++r) {
      int row = wm * 32 + fm * 16 + g * 4 + r;
      float s = redS[0][row] + redS[1][row] + redS[2][row] + redS[3][row];
      inv[fm][r] = 1.0f / s;
    }
  f32x4 acc2[2][12];
#pragma unroll
  for (int i = 0; i < 2; ++i)
#pragma unroll
    for (int j = 0; j < 12; ++j) acc2[i][j] = (f32x4){0.f, 0.f, 0.f, 0.f};
  const __bf16* XTb = XTbf + ((size_t)b * NH + wn * 192 + c) * NS + g * 8;
  const int r0 = wm * 32 + c;
  const int r1 = r0 + 16;
  for (int ks = 0; ks < NS; ks += 32) {
    int kk = ks + g * 8;
    bf16x8 a0 = *(const bf16x8*)&Plds[r0 * 512 + (kk ^ ((r0 & 7) << 3))];
    bf16x8 a1 = *(const bf16x8*)&Plds[r1 * 512 + (kk ^ ((r1 & 7) << 3))];
#pragma unroll
    for (int fn = 0; fn < 12; ++fn) {
      bf16x8 bb = *(const bf16x8*)(XTb + (size_t)fn * 16 * NS + ks);
      acc2[0][fn] = mfma_bf16(a0, bb, acc2[0][fn]);
      acc2[1][fn] = mfma_bf16(a1, bb, acc2[1][fn]);
    }
  }
  float* Ob = Out + ((size_t)b * NL + R0) * NH;
#pragma unroll
  for (int fm = 0; fm < 2; ++fm)
#pragma unroll
    for (int r = 0; r < 4; ++r) {
      int row = wm * 32 + fm * 16 + g * 4 + r;
      float sc = inv[fm][r];
#pragma unroll
      for (int fn = 0; fn < 12; ++fn) {
        int h = wn * 192 + fn * 16 + c;
        Ob[(size_t)row * NH + h] = acc2[fm][fn][r] * sc;
      }
    }
}

// ---------------------------------------------------------------------------
extern "C" void kernel_launch(void* const* d_in, const int* in_sizes, int n_in,
                              void* d_out, int out_size, void* d_ws, size_t ws_size,
                              hipStream_t stream) {
  const float* X = (const float*)d_in[0];   // [8,512,768] f32
  const void* masks = d_in[1];              // [8,1,512] bool (dtype probed)
  const float* E = (const float*)d_in[2];   // [8192,768] f32
  const float* W = (const float*)d_in[3];   // [768,768] f32
  float* Out = (float*)d_out;               // [8,8192,768] f32

  char* ws = (char*)d_ws;
  const size_t NEED = 99762432;

  if (ws_size >= NEED) {
    // ---- split path: 5 launches ----
    __bf16* Xbf  = (__bf16*)ws;                    //  6,291,456 B
    __bf16* Wbf  = (__bf16*)(ws + 6291456);        //  1,179,648 B
    __bf16* Ebf  = (__bf16*)(ws + 7471104);        // 12,582,912 B
    __bf16* Kbf  = (__bf16*)(ws + 20054016);       //  6,291,456 B
    __bf16* XTbf = (__bf16*)(ws + 26345472);       //  6,291,456 B
    __bf16* Pws  = (__bf16*)(ws + 32636928);       // 67,108,864 B
    float* mbias = (float*)(ws + 99745792);        //     16,384 B

    mask_kernel<<<1, 256, 0, stream>>>((const unsigned char*)masks, mbias);
    prep_kernel<<<5664, 256, 0, stream>>>(X, W, E, Xbf, XTbf);
    proj64_kernel<<<dim3(64, 12), 256, 0, stream>>>(Xbf, Wbf, Kbf);
    scores64_kernel<<<dim3(128, 8), 512, 0, stream>>>(Ebf, Kbf, mbias, Pws);
    pv_kernel<<<dim3(64, 6, 8), 256, 0, stream>>>(Pws, XTbf, Out);
  } else {
    // ---- round-1 fallback (25.2 MB ws) ----
    __bf16* Kbf  = (__bf16*)ws;
    __bf16* XTbf = (__bf16*)(ws + 6291456);
    __bf16* Ebf  = (__bf16*)(ws + 12582912);
    float* mbias = (float*)(ws + 25165824);
    int* flag    = (int*)(ws + 25182208);

    detect_mask_kernel<<<1, 256, 0, stream>>>((const unsigned char*)masks, flag);
    expand_mask_kernel<<<16, 256, 0, stream>>>(masks, flag, mbias);
    proj_kernel<<<dim3(64, 12), 256, 0, stream>>>(X, W, Kbf);
    transpose_kernel<<<dim3(12, 8, 8), 256, 0, stream>>>(X, XTbf);
    cast_kernel<<<3072, 256, 0, stream>>>(E, Ebf);
    label_attn_kernel<<<dim3(128, 8), 512, 0, stream>>>(Ebf, Kbf, XTbf, mbias, Out);
  }
}